// Round 8
// baseline (8997.885 us; speedup 1.0000x reference)
//
#include <hip/hip_runtime.h>
#include <cstdint>
#include <cstddef>

#define BB 16
#define NN 4096
#define SS 1024
#define KK 32
#define MROWS (BB*SS*KK)   // 524288 rows, one per (b,s,k)
#define EPSV 1e-5f
#define OUT_OFF1 (BB*3*SS) // 49152 floats: new_xyz chunk size

// ---------------- workspace layout (bytes), total ~22 MB ----------------
static constexpr size_t OFF_XYZT   = 0;                                    // float4[B*N]
static constexpr size_t OFF_NEWXYZ = OFF_XYZT   + (size_t)BB*NN*16;        // float4[B*S]
static constexpr size_t OFF_BALL   = OFF_NEWXYZ + (size_t)BB*SS*16;        // int[M]
static constexpr size_t OFF_STATS  = OFF_BALL   + (size_t)MROWS*4;         // float[512]
static constexpr size_t OFF_PT     = OFF_STATS  + 2048;                    // float[B*N*64]

// Non-contractible fp32 ops: numpy computes mul+add (never FMA). Forcing
// v_mul/v_add via _rn intrinsics removes any FMA-contraction divergence.
__device__ __forceinline__ float sq3(float x, float y, float z) {
  return __fadd_rn(__fadd_rn(__fmul_rn(x,x), __fmul_rn(y,y)), __fmul_rn(z,z));
}

// ---------------- transpose xyz (b,3,n) -> float4 (b,n,{x,y,z,0}) ----------------
__global__ __launch_bounds__(256) void transpose_xyz(const float* __restrict__ xyz,
                                                     float4* __restrict__ xyzt) {
  int b = blockIdx.x;
  int n = blockIdx.y*256 + threadIdx.x;
  const float* xb = xyz + (size_t)b*3*NN;
  xyzt[(size_t)b*NN + n] = make_float4(xb[n], xb[NN+n], xb[2*NN+n], 0.f);
}

// ---------------- naive transpose points (b,64,n) -> (b,n,64) ----------------
__global__ __launch_bounds__(256) void transpose_points_naive(const float* __restrict__ pts,
                                                              float* __restrict__ pt) {
  int f = blockIdx.x*256 + threadIdx.x;   // f = (b*NN + n)*64 + d
  int d = f & 63;
  int n = (f >> 6) & (NN-1);
  int b = f >> 18;
  pt[f] = pts[(size_t)((b << 6) | d)*NN + n];
}

// ---------------- farthest point sampling, fp32, FMA-proof ----------------
__global__ __launch_bounds__(1024) void fps_kernel(const float* __restrict__ xyz,
                                                   float4* __restrict__ newxyz,
                                                   float* __restrict__ out) {
  __shared__ float sx[NN], sy[NN], sz[NN];
  __shared__ unsigned long long red[2][16];
  int b = blockIdx.x, t = threadIdx.x;
  const float* xb = xyz + (size_t)b*3*NN;
  float px[4], py[4], pz[4], dd[4];
#pragma unroll
  for (int j = 0; j < 4; ++j) {
    int n = t + 1024*j;
    px[j] = xb[n]; py[j] = xb[NN+n]; pz[j] = xb[2*NN+n];
    sx[n] = px[j]; sy[n] = py[j]; sz[n] = pz[j];
    dd[j] = 1e10f;
  }
  int f = 0;
  __syncthreads();
  for (int i = 0; i < SS; ++i) {
    float cx = sx[f], cy = sy[f], cz = sz[f];
    if (t == 0) {
      newxyz[b*SS + i] = make_float4(cx, cy, cz, 0.f);
      out[(size_t)b*3*SS + i]        = cx;
      out[(size_t)b*3*SS + SS + i]   = cy;
      out[(size_t)b*3*SS + 2*SS + i] = cz;
    }
    if (i == SS-1) break;
    float bv = -1.f; int bn = 0;
#pragma unroll
    for (int j = 0; j < 4; ++j) {
      float dx = __fsub_rn(px[j], cx);
      float dy = __fsub_rn(py[j], cy);
      float dz = __fsub_rn(pz[j], cz);
      float d  = sq3(dx, dy, dz);                // ((dx^2+dy^2)+dz^2), no FMA
      float nd = dd[j] < d ? dd[j] : d;
      dd[j] = nd;
      if (nd > bv) { bv = nd; bn = t + 1024*j; } // strict > keeps smallest n
    }
#pragma unroll
    for (int m = 1; m < 64; m <<= 1) {
      float ov = __shfl_xor(bv, m, 64);
      int   on = __shfl_xor(bn, m, 64);
      if (ov > bv || (ov == bv && on < bn)) { bv = ov; bn = on; }
    }
    if ((t & 63) == 0)
      red[i&1][t>>6] = (((unsigned long long)__float_as_uint(bv)) << 32) | (unsigned)(NN-1-bn);
    __syncthreads();
    unsigned long long best = red[i&1][0];
#pragma unroll
    for (int w = 1; w < 16; ++w) { unsigned long long v = red[i&1][w]; if (v > best) best = v; }
    f = (NN-1) - (int)(best & 0xffffffffull);
  }
}

// ---------------- LITERAL ball query, FMA-proof fp32 ----------------
__global__ __launch_bounds__(256) void ball_literal(const float* __restrict__ xyz,
                                                    const float4* __restrict__ newxyz,
                                                    int* __restrict__ ball) {
  int bs = blockIdx.x*256 + threadIdx.x;   // 16384 groups
  int b = bs >> 10;
  const float* xb = xyz + (size_t)b*3*NN;
  float4 c = newxyz[bs];
  float sumS = sq3(c.x, c.y, c.z);
  int g[KK];
  int count = 0;
  for (int n = 0; n < NN; ++n) {
    float nx = xb[n], ny = xb[NN+n], nz = xb[2*NN+n];
    float sumN = sq3(nx, ny, nz);
    float dt   = __fadd_rn(__fadd_rn(__fmul_rn(c.x,nx), __fmul_rn(c.y,ny)), __fmul_rn(c.z,nz));
    float sqr  = __fsub_rn(__fadd_rn(sumS, sumN), __fmul_rn(2.0f, dt));
    if (!(sqr > 0.04f)) {                  // in-ball iff !(sqr > r^2), f32 threshold
      if (count < KK) g[count] = n;
      ++count;
    }
  }
  int m = count < KK ? count : KK;
  for (int i = m; i < KK; ++i) g[i] = NN-1;  // literal pad = N-1
  for (int i = 0; i < KK; ++i) ball[(size_t)bs*KK + i] = g[i];
}

// ---------------- NAIVE per-row register-pipeline MLP ----------------
// PASS 0: conv0 -> stats0
// PASS 1: conv0 -> BN0+relu -> conv1 -> stats1
// PASS 2: ... -> conv2 -> stats2
// PASS 3: ... -> conv2 -> BN2+relu -> atomicMax into out (literal maxpool)
template<int PASS>
__global__ __launch_bounds__(256) void naive_pass(
    const float* __restrict__ pt, const float4* __restrict__ xyzt,
    const float4* __restrict__ newxyz, const int* __restrict__ ball,
    const float* __restrict__ W0g, const float* __restrict__ b0g,
    const float* __restrict__ W1g, const float* __restrict__ b1g,
    const float* __restrict__ W2g, const float* __restrict__ b2g,
    const float* __restrict__ stats,
    const float* __restrict__ g0, const float* __restrict__ be0,
    const float* __restrict__ g1, const float* __restrict__ be1,
    const float* __restrict__ g2, const float* __restrict__ be2,
    float* __restrict__ statsOut, float* __restrict__ out) {
  __shared__ float sc0[64], sh0[64], sc1[64], sh1[64], sc2[128], sh2[128];
  __shared__ float scr[256];
  int t = threadIdx.x;
  int lane = t & 63;
  if constexpr (PASS >= 1) {
    if (t < 64) {
      float mean = stats[t] * (1.0f/MROWS);
      float var  = stats[64+t] * (1.0f/MROWS) - mean*mean;
      float s = g0[t] / sqrtf(var + EPSV);
      sc0[t] = s; sh0[t] = be0[t] - mean*s;
    }
  }
  if constexpr (PASS >= 2) {
    if (t < 64) {
      float mean = stats[128+t] * (1.0f/MROWS);
      float var  = stats[192+t] * (1.0f/MROWS) - mean*mean;
      float s = g1[t] / sqrtf(var + EPSV);
      sc1[t] = s; sh1[t] = be1[t] - mean*s;
    }
  }
  if constexpr (PASS == 3) {
    if (t < 128) {
      float mean = stats[256+t] * (1.0f/MROWS);
      float var  = stats[384+t] * (1.0f/MROWS) - mean*mean;
      float s = g2[t] / sqrtf(var + EPSV);
      sc2[t] = s; sh2[t] = be2[t] - mean*s;
    }
  }
  scr[t] = 0.f;
  __syncthreads();

  int r  = blockIdx.x*256 + t;    // row id < 524288
  int n  = ball[r];
  int bs = r >> 5;
  int b  = r >> 15;
  int s  = bs & (SS-1);

  float f[67];
  {
    float4 pz = xyzt[b*NN + n];
    float4 q  = newxyz[bs];
    f[0] = pz.x - q.x; f[1] = pz.y - q.y; f[2] = pz.z - q.z;
    const float* pr = pt + (size_t)(b*NN + n)*64;
    for (int c = 0; c < 64; ++c) f[3+c] = pr[c];
  }

  // conv0: direct W0[o*67 + c], c order == reference concat order (xyz3, points64)
  float y0[64];
  for (int o = 0; o < 64; ++o) {
    float a = b0g[o];
    for (int c = 0; c < 67; ++c) a = fmaf(f[c], W0g[o*67 + c], a);
    y0[o] = a;
  }

  auto flush64 = [&](float (&y)[64]) {   // sum/sumsq of y over all rows
    for (int ch = 0; ch < 8; ++ch) {
      float vS[8], vQ[8];
      for (int j = 0; j < 8; ++j) { float v = y[ch*8+j]; vS[j] = v; vQ[j] = v*v; }
      for (int m = 1; m <= 32; m <<= 1)
        for (int j = 0; j < 8; ++j) {
          vS[j] += __shfl_xor(vS[j], m, 64);
          vQ[j] += __shfl_xor(vQ[j], m, 64);
        }
      if (lane == 0)
        for (int j = 0; j < 8; ++j) {
          atomicAdd(&scr[ch*8+j], vS[j]);
          atomicAdd(&scr[64+ch*8+j], vQ[j]);
        }
    }
  };

  if constexpr (PASS == 0) {
    flush64(y0);
  } else {
    for (int o = 0; o < 64; ++o) y0[o] = fmaxf(0.f, fmaf(y0[o], sc0[o], sh0[o]));

    float y1[64];
    for (int o = 0; o < 64; ++o) {
      float a = b1g[o];
      const float* wr = W1g + o*64;
      for (int c = 0; c < 64; ++c) a = fmaf(y0[c], wr[c], a);
      y1[o] = a;
    }

    if constexpr (PASS == 1) {
      flush64(y1);
    } else {
      for (int o = 0; o < 64; ++o) y1[o] = fmaxf(0.f, fmaf(y1[o], sc1[o], sh1[o]));

      if constexpr (PASS == 2) {
        // conv2: stats only
        for (int ch = 0; ch < 16; ++ch) {
          float vS[8], vQ[8];
          for (int j = 0; j < 8; ++j) {
            int o = ch*8 + j;
            float a = b2g[o];
            const float* wr = W2g + o*64;
            for (int c = 0; c < 64; ++c) a = fmaf(y1[c], wr[c], a);
            vS[j] = a; vQ[j] = a*a;
          }
          for (int m = 1; m <= 32; m <<= 1)
            for (int j = 0; j < 8; ++j) {
              vS[j] += __shfl_xor(vS[j], m, 64);
              vQ[j] += __shfl_xor(vQ[j], m, 64);
            }
          if (lane == 0)
            for (int j = 0; j < 8; ++j) {
              atomicAdd(&scr[ch*8+j], vS[j]);
              atomicAdd(&scr[128+ch*8+j], vQ[j]);
            }
        }
      } else {
        // PASS 3: literal BN2+relu then atomicMax pool into output (relu>=0, uint order)
        unsigned* outU = (unsigned*)(out + OUT_OFF1);
        for (int ch = 0; ch < 16; ++ch) {
          for (int j = 0; j < 8; ++j) {
            int o = ch*8 + j;
            float a = b2g[o];
            const float* wr = W2g + o*64;
            for (int c = 0; c < 64; ++c) a = fmaf(y1[c], wr[c], a);
            float v = fmaxf(0.f, fmaf(a, sc2[o], sh2[o]));
            atomicMax(&outU[((size_t)b*128 + o)*SS + s], __float_as_uint(v));
          }
        }
      }
    }
  }

  if constexpr (PASS <= 2) {
    __syncthreads();
    constexpr int NSTAT = (PASS == 2) ? 256 : 128;
    if (t < NSTAT) atomicAdd(&statsOut[t], scr[t]);
  }
}

extern "C" void kernel_launch(void* const* d_in, const int* in_sizes, int n_in,
                              void* d_out, int out_size, void* d_ws, size_t ws_size,
                              hipStream_t stream) {
  const float* xyz = (const float*)d_in[0];
  const float* pts = (const float*)d_in[1];
  const float* W0  = (const float*)d_in[2];
  const float* b0  = (const float*)d_in[3];
  const float* g0  = (const float*)d_in[4];
  const float* be0 = (const float*)d_in[5];
  const float* W1  = (const float*)d_in[6];
  const float* b1  = (const float*)d_in[7];
  const float* g1  = (const float*)d_in[8];
  const float* be1 = (const float*)d_in[9];
  const float* W2  = (const float*)d_in[10];
  const float* b2  = (const float*)d_in[11];
  const float* g2  = (const float*)d_in[12];
  const float* be2 = (const float*)d_in[13];
  float* out = (float*)d_out;
  char* ws = (char*)d_ws;

  float4* xyzt   = (float4*)(ws + OFF_XYZT);
  float4* newxyz = (float4*)(ws + OFF_NEWXYZ);
  int*    ball   = (int*)(ws + OFF_BALL);
  float*  stats  = (float*)(ws + OFF_STATS);
  float*  pt     = (float*)(ws + OFF_PT);

  hipMemsetAsync(stats, 0, 512*sizeof(float), stream);
  hipMemsetAsync(out + OUT_OFF1, 0, (size_t)BB*128*SS*sizeof(float), stream);
  transpose_xyz<<<dim3(BB, NN/256), 256, 0, stream>>>(xyz, xyzt);
  transpose_points_naive<<<(BB*NN*64)/256, 256, 0, stream>>>(pts, pt);
  fps_kernel<<<BB, 1024, 0, stream>>>(xyz, newxyz, out);
  ball_literal<<<BB*SS/256, 256, 0, stream>>>(xyz, newxyz, ball);
  naive_pass<0><<<MROWS/256, 256, 0, stream>>>(pt, xyzt, newxyz, ball, W0, b0, W1, b1, W2, b2,
      stats, g0, be0, g1, be1, g2, be2, stats, out);
  naive_pass<1><<<MROWS/256, 256, 0, stream>>>(pt, xyzt, newxyz, ball, W0, b0, W1, b1, W2, b2,
      stats, g0, be0, g1, be1, g2, be2, stats + 128, out);
  naive_pass<2><<<MROWS/256, 256, 0, stream>>>(pt, xyzt, newxyz, ball, W0, b0, W1, b1, W2, b2,
      stats, g0, be0, g1, be1, g2, be2, stats + 256, out);
  naive_pass<3><<<MROWS/256, 256, 0, stream>>>(pt, xyzt, newxyz, ball, W0, b0, W1, b1, W2, b2,
      stats, g0, be0, g1, be1, g2, be2, nullptr, out);
}

// Round 9
// 4301.871 us; speedup vs baseline: 2.0916x; 2.0916x over previous
//
#include <hip/hip_runtime.h>
#include <cstdint>
#include <cstddef>

#define BB 16
#define NN 4096
#define SS 1024
#define KK 32
#define MROWS (BB*SS*KK)   // 524288 rows, one per (b,s,k)
#define EPSV 1e-5f
#define OUT_OFF1 (BB*3*SS) // 49152 floats: new_xyz chunk size

// ---------------- workspace layout (bytes), total ~37 MB ----------------
static constexpr size_t OFF_XYZT   = 0;                                    // float4[B*N]
static constexpr size_t OFF_NEWXYZ = OFF_XYZT   + (size_t)BB*NN*16;        // float4[B*S]
static constexpr size_t OFF_BALL   = OFF_NEWXYZ + (size_t)BB*SS*16;        // int[M]
static constexpr size_t OFF_STATS  = OFF_BALL   + (size_t)MROWS*4;        // float[512]
static constexpr size_t OFF_PT     = OFF_STATS  + 2048;                    // float[B*N*64]
static constexpr size_t OFF_YMAX   = OFF_PT     + (size_t)BB*NN*64*4;      // float[B*S*128]
static constexpr size_t OFF_YMIN   = OFF_YMAX   + (size_t)BB*SS*128*4;     // float[B*S*128]

// Non-contractible fp32 ops: numpy computes mul+add (never FMA). hipcc ignores
// `#pragma clang fp contract(off)` for device code (proven rounds 1-8) — the
// _rn intrinsics are the only reliable way to match np's discrete decisions.
__device__ __forceinline__ float sq3(float x, float y, float z) {
  return __fadd_rn(__fadd_rn(__fmul_rn(x,x), __fmul_rn(y,y)), __fmul_rn(z,z));
}

// ---------------- transpose xyz (b,3,n) -> float4 (b,n,{x,y,z,0}) ----------------
__global__ __launch_bounds__(256) void transpose_xyz(const float* __restrict__ xyz,
                                                     float4* __restrict__ xyzt) {
  int b = blockIdx.x;
  int n = blockIdx.y*256 + threadIdx.x;
  const float* xb = xyz + (size_t)b*3*NN;
  xyzt[(size_t)b*NN + n] = make_float4(xb[n], xb[NN+n], xb[2*NN+n], 0.f);
}

// ---------------- tiled transpose points (b,64,n) -> (b,n,64) ----------------
__global__ __launch_bounds__(256) void transpose_points(const float* __restrict__ pts,
                                                        float* __restrict__ pt) {
  __shared__ float tl[64*65];
  int b = blockIdx.x, n0 = blockIdx.y*64;
  int t = threadIdx.x;
  int ln = t & 63, hi = t >> 6;
#pragma unroll
  for (int i = 0; i < 16; ++i) {
    int c = 4*i + hi;
    tl[c*65 + ln] = pts[((size_t)b*64 + c)*NN + n0 + ln];
  }
  __syncthreads();
#pragma unroll
  for (int i = 0; i < 16; ++i) {
    int nn = hi + 4*i;
    pt[((size_t)b*NN + n0 + nn)*64 + ln] = tl[ln*65 + nn];
  }
}

// ---------------- farthest point sampling, fp32, FMA-proof (bit-verified) ----------------
__global__ __launch_bounds__(1024) void fps_kernel(const float* __restrict__ xyz,
                                                   float4* __restrict__ newxyz,
                                                   float* __restrict__ out) {
  __shared__ float sx[NN], sy[NN], sz[NN];
  __shared__ unsigned long long red[2][16];
  int b = blockIdx.x, t = threadIdx.x;
  const float* xb = xyz + (size_t)b*3*NN;
  float px[4], py[4], pz[4], dd[4];
#pragma unroll
  for (int j = 0; j < 4; ++j) {
    int n = t + 1024*j;
    px[j] = xb[n]; py[j] = xb[NN+n]; pz[j] = xb[2*NN+n];
    sx[n] = px[j]; sy[n] = py[j]; sz[n] = pz[j];
    dd[j] = 1e10f;
  }
  int f = 0;
  __syncthreads();
  for (int i = 0; i < SS; ++i) {
    float cx = sx[f], cy = sy[f], cz = sz[f];
    if (t == 0) {
      newxyz[b*SS + i] = make_float4(cx, cy, cz, 0.f);
      out[(size_t)b*3*SS + i]        = cx;
      out[(size_t)b*3*SS + SS + i]   = cy;
      out[(size_t)b*3*SS + 2*SS + i] = cz;
    }
    if (i == SS-1) break;
    float bv = -1.f; int bn = 0;
#pragma unroll
    for (int j = 0; j < 4; ++j) {
      float dx = __fsub_rn(px[j], cx);
      float dy = __fsub_rn(py[j], cy);
      float dz = __fsub_rn(pz[j], cz);
      float d  = sq3(dx, dy, dz);                // ((dx^2+dy^2)+dz^2), no FMA
      float nd = dd[j] < d ? dd[j] : d;
      dd[j] = nd;
      if (nd > bv) { bv = nd; bn = t + 1024*j; } // strict > keeps smallest n
    }
#pragma unroll
    for (int m = 1; m < 64; m <<= 1) {
      float ov = __shfl_xor(bv, m, 64);
      int   on = __shfl_xor(bn, m, 64);
      if (ov > bv || (ov == bv && on < bn)) { bv = ov; bn = on; }
    }
    if ((t & 63) == 0)
      red[i&1][t>>6] = (((unsigned long long)__float_as_uint(bv)) << 32) | (unsigned)(NN-1-bn);
    __syncthreads();
    unsigned long long best = red[i&1][0];
#pragma unroll
    for (int w = 1; w < 16; ++w) { unsigned long long v = red[i&1][w]; if (v > best) best = v; }
    f = (NN-1) - (int)(best & 0xffffffffull);
  }
}

// ---------------- LITERAL ball query, FMA-proof fp32 (verified) ----------------
__global__ __launch_bounds__(256) void ball_literal(const float* __restrict__ xyz,
                                                    const float4* __restrict__ newxyz,
                                                    int* __restrict__ ball) {
  int bs = blockIdx.x*256 + threadIdx.x;   // 16384 groups
  int b = bs >> 10;
  const float* xb = xyz + (size_t)b*3*NN;
  float4 c = newxyz[bs];
  float sumS = sq3(c.x, c.y, c.z);
  int g[KK];
  int count = 0;
  for (int n = 0; n < NN; ++n) {
    float nx = xb[n], ny = xb[NN+n], nz = xb[2*NN+n];
    float sumN = sq3(nx, ny, nz);
    float dt   = __fadd_rn(__fadd_rn(__fmul_rn(c.x,nx), __fmul_rn(c.y,ny)), __fmul_rn(c.z,nz));
    float sqr  = __fsub_rn(__fadd_rn(sumS, sumN), __fmul_rn(2.0f, dt));
    if (!(sqr > 0.04f)) {
      if (count < KK) g[count] = n;
      ++count;
    }
  }
  int m = count < KK ? count : KK;
  for (int i = m; i < KK; ++i) g[i] = NN-1;  // literal pad = N-1 (verified)
  for (int i = 0; i < KK; ++i) ball[(size_t)bs*KK + i] = g[i];
}

// ---------------- fused LDS-tiled recompute passes (semantics-verified r3<->r8) ----------------
// PASS 0: gather -> conv0 -> stats0
// PASS 1: gather -> conv0 -> BN0+relu -> conv1 -> stats1
// PASS 2: ... -> conv2 (2 halves) -> stats2 + per-(b,s) max/min over k
template<int PASS>
__global__ __launch_bounds__(256) void fused_kernel(
    const float* __restrict__ pt, const float4* __restrict__ xyzt,
    const float4* __restrict__ newxyz, const int* __restrict__ ball,
    const float* __restrict__ W0g, const float* __restrict__ b0g,
    const float* __restrict__ W1g, const float* __restrict__ b1g,
    const float* __restrict__ W2g, const float* __restrict__ b2g,
    const float* __restrict__ stats,
    const float* __restrict__ g0, const float* __restrict__ be0,
    const float* __restrict__ g1, const float* __restrict__ be1,
    float* __restrict__ statsOut,
    float* __restrict__ ymax, float* __restrict__ ymin) {
  __shared__ float4 Xs4[128*17];     // 128 rows x 68 floats
  __shared__ float4 Wb4[68*16];      // up to 68 rows x 64 cols
  __shared__ float sc0[64], sh0[64], sc1[64], sh1[64];
  float* Wb = (float*)Wb4;

  int t = threadIdx.x;
  int tc = t & 15;            // output col group (4 cols)
  int wv = t >> 6;            // wave -> 32-row band (one (b,s) group)
  int trs = (t >> 4) & 3;     // sub-row

  if constexpr (PASS >= 1) {
    if (t < 64) {
      float mean = stats[t] * (1.0f/MROWS);
      float var  = stats[64+t] * (1.0f/MROWS) - mean*mean;
      float s    = g0[t] / sqrtf(var + EPSV);
      sc0[t] = s; sh0[t] = be0[t] - mean*s;
    }
  }
  if constexpr (PASS == 2) {
    if (t < 64) {
      float mean = stats[128+t] * (1.0f/MROWS);
      float var  = stats[192+t] * (1.0f/MROWS) - mean*mean;
      float s    = g1[t] / sqrtf(var + EPSV);
      sc1[t] = s; sh1[t] = be1[t] - mean*s;
    }
  }

  float bj0[4], bj1[4], bj2[2][4];
#pragma unroll
  for (int j = 0; j < 4; ++j) {
    bj0[j] = b0g[tc*4 + j];
    if constexpr (PASS >= 1) bj1[j] = b1g[tc*4 + j];
    if constexpr (PASS == 2) { bj2[0][j] = b2g[tc*4 + j]; bj2[1][j] = b2g[64 + tc*4 + j]; }
  }

  float accS[4] = {0,0,0,0}, accQ[4] = {0,0,0,0};
  float accS2[2][4] = {{0,0,0,0},{0,0,0,0}};
  float accQ2[2][4] = {{0,0,0,0},{0,0,0,0}};

  auto loadW0 = [&]() {
    for (int idx = t; idx < 68*64; idx += 256) {
      int cc = idx >> 6, o = idx & 63;
      float v = 0.f;
      if (cc < 67) v = W0g[o*67 + (cc < 64 ? cc+3 : cc-64)];  // LDS rows: [points64, xyz3, 0]
      Wb[idx] = v;
    }
  };
  auto loadW64 = [&](const float* Wg) {
    for (int idx = t; idx < 64*64; idx += 256) {
      int cc = idx >> 6, o = idx & 63;
      Wb[idx] = Wg[o*64 + cc];
    }
  };
  auto conv = [&](int C4N, float (&acc)[8][4], const float (&bj)[4]) {
#pragma unroll
    for (int i = 0; i < 8; ++i)
#pragma unroll
      for (int j = 0; j < 4; ++j) acc[i][j] = bj[j];
    for (int c4 = 0; c4 < C4N; ++c4) {
      float4 a[8];
#pragma unroll
      for (int i = 0; i < 8; ++i) a[i] = Xs4[(32*wv + trs + 4*i)*17 + c4];
      float4 w0 = Wb4[(4*c4+0)*16 + tc];
      float4 w1 = Wb4[(4*c4+1)*16 + tc];
      float4 w2 = Wb4[(4*c4+2)*16 + tc];
      float4 w3 = Wb4[(4*c4+3)*16 + tc];
#pragma unroll
      for (int i = 0; i < 8; ++i) {
        acc[i][0] = fmaf(a[i].x, w0.x, acc[i][0]); acc[i][1] = fmaf(a[i].x, w0.y, acc[i][1]);
        acc[i][2] = fmaf(a[i].x, w0.z, acc[i][2]); acc[i][3] = fmaf(a[i].x, w0.w, acc[i][3]);
        acc[i][0] = fmaf(a[i].y, w1.x, acc[i][0]); acc[i][1] = fmaf(a[i].y, w1.y, acc[i][1]);
        acc[i][2] = fmaf(a[i].y, w1.z, acc[i][2]); acc[i][3] = fmaf(a[i].y, w1.w, acc[i][3]);
        acc[i][0] = fmaf(a[i].z, w2.x, acc[i][0]); acc[i][1] = fmaf(a[i].z, w2.y, acc[i][1]);
        acc[i][2] = fmaf(a[i].z, w2.z, acc[i][2]); acc[i][3] = fmaf(a[i].z, w2.w, acc[i][3]);
        acc[i][0] = fmaf(a[i].w, w3.x, acc[i][0]); acc[i][1] = fmaf(a[i].w, w3.y, acc[i][1]);
        acc[i][2] = fmaf(a[i].w, w3.z, acc[i][2]); acc[i][3] = fmaf(a[i].w, w3.w, acc[i][3]);
      }
    }
  };
  auto bnstore = [&](float (&acc)[8][4], const float* sc, const float* sh) {
    float s0 = sc[tc*4], s1 = sc[tc*4+1], s2 = sc[tc*4+2], s3 = sc[tc*4+3];
    float h0 = sh[tc*4], h1 = sh[tc*4+1], h2 = sh[tc*4+2], h3 = sh[tc*4+3];
#pragma unroll
    for (int i = 0; i < 8; ++i)
      Xs4[(32*wv + trs + 4*i)*17 + tc] = make_float4(
          fmaxf(0.f, fmaf(acc[i][0], s0, h0)), fmaxf(0.f, fmaf(acc[i][1], s1, h1)),
          fmaxf(0.f, fmaf(acc[i][2], s2, h2)), fmaxf(0.f, fmaf(acc[i][3], s3, h3)));
  };
  auto accum = [&](float (&acc)[8][4], float (&aS)[4], float (&aQ)[4]) {
#pragma unroll
    for (int i = 0; i < 8; ++i)
#pragma unroll
      for (int j = 0; j < 4; ++j) { float v = acc[i][j]; aS[j] += v; aQ[j] = fmaf(v, v, aQ[j]); }
  };
  auto maxmin = [&](float (&acc)[8][4], int h, int tile) {
    float vmx[4], vmn[4];
#pragma unroll
    for (int j = 0; j < 4; ++j) {
      float mx = acc[0][j], mn = acc[0][j];
#pragma unroll
      for (int i = 1; i < 8; ++i) { mx = fmaxf(mx, acc[i][j]); mn = fminf(mn, acc[i][j]); }
      vmx[j] = mx; vmn[j] = mn;
    }
#pragma unroll
    for (int m = 16; m <= 32; m <<= 1)
#pragma unroll
      for (int j = 0; j < 4; ++j) {
        vmx[j] = fmaxf(vmx[j], __shfl_xor(vmx[j], m, 64));
        vmn[j] = fminf(vmn[j], __shfl_xor(vmn[j], m, 64));
      }
    if ((t & 63) < 16) {
      size_t gg = (size_t)tile*4 + wv;
      ((float4*)(ymax + gg*128 + h*64 + tc*4))[0] = make_float4(vmx[0], vmx[1], vmx[2], vmx[3]);
      ((float4*)(ymin + gg*128 + h*64 + tc*4))[0] = make_float4(vmn[0], vmn[1], vmn[2], vmn[3]);
    }
  };

  for (int tile = blockIdx.x; tile < MROWS/128; tile += gridDim.x) {
    // ---- stage gathered feat tile ----
    {
      int rr = t >> 1, p = t & 1;
      int r = tile*128 + rr;
      int n = ball[r];
      int bb2 = r >> 15;
      const float4* src = (const float4*)(pt + ((size_t)(bb2*NN + n))*64) + 8*p;
#pragma unroll
      for (int jj = 0; jj < 8; ++jj) Xs4[rr*17 + 8*p + jj] = src[jj];
      if (p == 0) {
        float4 pz = xyzt[bb2*NN + n];
        float4 q  = newxyz[r >> 5];
        float* X = (float*)Xs4;
        X[rr*68 + 64] = pz.x - q.x;
        X[rr*68 + 65] = pz.y - q.y;
        X[rr*68 + 66] = pz.z - q.z;
        X[rr*68 + 67] = 0.f;
      }
    }
    loadW0();
    __syncthreads();

    float acc[8][4];
    conv(17, acc, bj0);                       // conv0 (67+pad inputs)
    if constexpr (PASS == 0) {
      accum(acc, accS, accQ);
      __syncthreads();
      continue;
    }

    __syncthreads();
    bnstore(acc, sc0, sh0);                   // y0 = relu(BN0(conv0)) -> Xs
    loadW64(W1g);
    __syncthreads();

    float acc1[8][4];
    conv(16, acc1, bj1);                      // conv1
    if constexpr (PASS == 1) {
      accum(acc1, accS, accQ);
      __syncthreads();
      continue;
    }

    if constexpr (PASS == 2) {
      __syncthreads();
      bnstore(acc1, sc1, sh1);                // y1 = relu(BN1(conv1)) -> Xs
      loadW64(W2g);                           // W2 rows 0..63
      __syncthreads();

      float acc2[8][4];
      conv(16, acc2, bj2[0]);                 // conv2 half 0
      accum(acc2, accS2[0], accQ2[0]);
      maxmin(acc2, 0, tile);
      __syncthreads();
      loadW64(W2g + 64*64);                   // W2 rows 64..127
      __syncthreads();

      conv(16, acc2, bj2[1]);                 // conv2 half 1
      accum(acc2, accS2[1], accQ2[1]);
      maxmin(acc2, 1, tile);
      __syncthreads();
    }
  }

  // ---- stats flush: regs -> LDS atomics -> global atomics ----
  float* scratch = (float*)Xs4;
  constexpr int NSTAT = (PASS == 2) ? 256 : 128;
  if (t < NSTAT) scratch[t] = 0.f;
  __syncthreads();
  if constexpr (PASS <= 1) {
#pragma unroll
    for (int j = 0; j < 4; ++j) {
      atomicAdd(&scratch[tc*4 + j], accS[j]);
      atomicAdd(&scratch[64 + tc*4 + j], accQ[j]);
    }
  } else {
#pragma unroll
    for (int h = 0; h < 2; ++h)
#pragma unroll
      for (int j = 0; j < 4; ++j) {
        atomicAdd(&scratch[h*64 + tc*4 + j], accS2[h][j]);
        atomicAdd(&scratch[128 + h*64 + tc*4 + j], accQ2[h][j]);
      }
  }
  __syncthreads();
  if (t < NSTAT) atomicAdd(&statsOut[t], scratch[t]);
}

// ---------------- epilogue: BN2+relu on max/min-pooled conv2, transposed write ----------------
__global__ __launch_bounds__(256) void final_kernel(const float4* __restrict__ ymax4,
                                                    const float4* __restrict__ ymin4,
                                                    const float* __restrict__ stats2,
                                                    const float* __restrict__ g2,
                                                    const float* __restrict__ be2,
                                                    float* __restrict__ out) {
  __shared__ float sc3[128], sh3[128];
  __shared__ float tile[64*129];
  int t = threadIdx.x;
  if (t < 128) {
    float mean = stats2[t] * (1.0f/MROWS);
    float var  = stats2[128+t] * (1.0f/MROWS) - mean*mean;
    float sc   = g2[t] / sqrtf(var + EPSV);
    sc3[t] = sc; sh3[t] = be2[t] - mean*sc;
  }
  __syncthreads();
  int b = blockIdx.x, s0 = blockIdx.y*64;
#pragma unroll
  for (int pass = 0; pass < 8; ++pass) {
    int srow = pass*8 + (t >> 5);
    int o4 = (t & 31)*4;
    size_t base = (size_t)(b*SS + s0 + srow)*32 + (t & 31);
    float4 vx = ymax4[base], vn = ymin4[base];
#pragma unroll
    for (int e = 0; e < 4; ++e) {
      int o = o4 + e;
      float sc = sc3[o];
      float v = sc > 0.f ? ((const float*)&vx)[e] : ((const float*)&vn)[e];
      tile[srow*129 + o] = fmaxf(0.f, fmaf(v, sc, sh3[o]));
    }
  }
  __syncthreads();
  int s = t & 63;
  size_t obase = (size_t)OUT_OFF1 + (size_t)b*128*SS + s0 + s;
#pragma unroll
  for (int oi = 0; oi < 32; ++oi) {
    int o = (t >> 6) + 4*oi;
    out[obase + (size_t)o*SS] = tile[s*129 + o];
  }
}

extern "C" void kernel_launch(void* const* d_in, const int* in_sizes, int n_in,
                              void* d_out, int out_size, void* d_ws, size_t ws_size,
                              hipStream_t stream) {
  const float* xyz = (const float*)d_in[0];
  const float* pts = (const float*)d_in[1];
  const float* W0  = (const float*)d_in[2];
  const float* b0  = (const float*)d_in[3];
  const float* g0  = (const float*)d_in[4];
  const float* be0 = (const float*)d_in[5];
  const float* W1  = (const float*)d_in[6];
  const float* b1  = (const float*)d_in[7];
  const float* g1  = (const float*)d_in[8];
  const float* be1 = (const float*)d_in[9];
  const float* W2  = (const float*)d_in[10];
  const float* b2  = (const float*)d_in[11];
  const float* g2  = (const float*)d_in[12];
  const float* be2 = (const float*)d_in[13];
  float* out = (float*)d_out;
  char* ws = (char*)d_ws;

  float4* xyzt   = (float4*)(ws + OFF_XYZT);
  float4* newxyz = (float4*)(ws + OFF_NEWXYZ);
  int*    ball   = (int*)(ws + OFF_BALL);
  float*  stats  = (float*)(ws + OFF_STATS);
  float*  pt     = (float*)(ws + OFF_PT);
  float*  ymax   = (float*)(ws + OFF_YMAX);
  float*  ymin   = (float*)(ws + OFF_YMIN);

  hipMemsetAsync(stats, 0, 512*sizeof(float), stream);
  transpose_xyz<<<dim3(BB, NN/256), 256, 0, stream>>>(xyz, xyzt);
  transpose_points<<<dim3(BB, NN/64), 256, 0, stream>>>(pts, pt);
  fps_kernel<<<BB, 1024, 0, stream>>>(xyz, newxyz, out);
  ball_literal<<<BB*SS/256, 256, 0, stream>>>(xyz, newxyz, ball);
  fused_kernel<0><<<1024, 256, 0, stream>>>(pt, xyzt, newxyz, ball, W0, b0, W1, b1, W2, b2,
      stats, g0, be0, g1, be1, stats, ymax, ymin);
  fused_kernel<1><<<1024, 256, 0, stream>>>(pt, xyzt, newxyz, ball, W0, b0, W1, b1, W2, b2,
      stats, g0, be0, g1, be1, stats + 128, ymax, ymin);
  fused_kernel<2><<<1024, 256, 0, stream>>>(pt, xyzt, newxyz, ball, W0, b0, W1, b1, W2, b2,
      stats, g0, be0, g1, be1, stats + 256, ymax, ymin);
  final_kernel<<<dim3(BB, SS/64), 256, 0, stream>>>((const float4*)ymax, (const float4*)ymin,
      stats + 256, g2, be2, out);
}

// Round 10
// 1643.640 us; speedup vs baseline: 5.4744x; 2.6173x over previous
//
#include <hip/hip_runtime.h>
#include <cstdint>
#include <cstddef>

#define BB 16
#define NN 4096
#define SS 1024
#define KK 32
#define MROWS (BB*SS*KK)   // 524288 rows, one per (b,s,k)
#define EPSV 1e-5f
#define OUT_OFF1 (BB*3*SS) // 49152 floats: new_xyz chunk size

// ---------------- workspace layout (bytes), total ~37 MB ----------------
static constexpr size_t OFF_XYZT   = 0;                                    // float4[B*N]
static constexpr size_t OFF_NEWXYZ = OFF_XYZT   + (size_t)BB*NN*16;        // float4[B*S]
static constexpr size_t OFF_BALL   = OFF_NEWXYZ + (size_t)BB*SS*16;        // int[M]
static constexpr size_t OFF_STATS  = OFF_BALL   + (size_t)MROWS*4;         // float[512]
static constexpr size_t OFF_PT     = OFF_STATS  + 2048;                    // float[B*N*64]
static constexpr size_t OFF_YMAX   = OFF_PT     + (size_t)BB*NN*64*4;      // float[B*S*128]
static constexpr size_t OFF_YMIN   = OFF_YMAX   + (size_t)BB*SS*128*4;     // float[B*S*128]

// Non-contractible fp32 ops: numpy computes mul+add (never FMA). hipcc ignores
// `#pragma clang fp contract(off)` for device code (proven rounds 1-8) — the
// _rn intrinsics are the only reliable way to match np's discrete decisions.
__device__ __forceinline__ float sq3(float x, float y, float z) {
  return __fadd_rn(__fadd_rn(__fmul_rn(x,x), __fmul_rn(y,y)), __fmul_rn(z,z));
}

// ---------------- fused FPS (blocks 0-15) + transposes (blocks 16-1039) ----------------
// FPS: 256 thr x 16 pts, packed-u64-key argmax (value bits << 32 | (4095-n)):
// identical total order to the verified (value, smaller-index) tie-break.
// Transpose blocks overlap on the otherwise-idle 240 CUs.
__global__ __launch_bounds__(256) void fps_trans_kernel(const float* __restrict__ xyz,
                                                        const float* __restrict__ pts,
                                                        float4* __restrict__ xyzt,
                                                        float* __restrict__ pt,
                                                        float4* __restrict__ newxyz,
                                                        float* __restrict__ out) {
  __shared__ float sx[NN], sy[NN], sz[NN];
  __shared__ unsigned long long red[2][4];
  __shared__ float tl[64*65];
  int t = threadIdx.x;

  if (blockIdx.x >= 16) {
    // ---------------- transpose work ----------------
    int k = blockIdx.x - 16;            // 1024 blocks: b = k>>6, n0 = (k&63)*64
    int b = k >> 6, n0 = (k & 63) * 64;
    int ln = t & 63, hi = t >> 6;
#pragma unroll
    for (int i = 0; i < 16; ++i) {
      int c = 4*i + hi;
      tl[c*65 + ln] = pts[((size_t)b*64 + c)*NN + n0 + ln];
    }
    if (t < 64) {
      int n = n0 + t;
      const float* xb = xyz + (size_t)b*3*NN;
      xyzt[(size_t)b*NN + n] = make_float4(xb[n], xb[NN+n], xb[2*NN+n], 0.f);
    }
    __syncthreads();
#pragma unroll
    for (int i = 0; i < 16; ++i) {
      int nn = hi + 4*i;
      pt[((size_t)b*NN + n0 + nn)*64 + ln] = tl[ln*65 + nn];
    }
    return;
  }

  // ---------------- FPS ----------------
  int b = blockIdx.x;
  int lane = t & 63, wv = t >> 6;
  const float* xb = xyz + (size_t)b*3*NN;
  float px[16], py[16], pz[16], dd[16];
#pragma unroll
  for (int j = 0; j < 16; ++j) {
    int n = t + 256*j;
    px[j] = xb[n]; py[j] = xb[NN+n]; pz[j] = xb[2*NN+n];
    sx[n] = px[j]; sy[n] = py[j]; sz[n] = pz[j];
    dd[j] = 1e10f;
  }
  int f = 0;
  __syncthreads();
  for (int i = 0; i < SS; ++i) {
    float cx = sx[f], cy = sy[f], cz = sz[f];
    if (t == 0) {
      newxyz[b*SS + i] = make_float4(cx, cy, cz, 0.f);
      out[(size_t)b*3*SS + i]        = cx;
      out[(size_t)b*3*SS + SS + i]   = cy;
      out[(size_t)b*3*SS + 2*SS + i] = cz;
    }
    if (i == SS-1) break;
    unsigned long long key[16];
#pragma unroll
    for (int j = 0; j < 16; ++j) {
      float dx = __fsub_rn(px[j], cx);
      float dy = __fsub_rn(py[j], cy);
      float dz = __fsub_rn(pz[j], cz);
      float d  = sq3(dx, dy, dz);                // ((dx^2+dy^2)+dz^2), no FMA
      float nd = dd[j] < d ? dd[j] : d;
      dd[j] = nd;
      key[j] = (((unsigned long long)__float_as_uint(nd)) << 32)
             | (unsigned)(NN-1 - (t + 256*j));
    }
    // in-thread tree max (15 ops, 4 dependent levels)
#pragma unroll
    for (int w = 8; w >= 1; w >>= 1)
#pragma unroll
      for (int q = 0; q < w; ++q)
        key[q] = key[q] > key[q+w] ? key[q] : key[q+w];
    unsigned long long bk = key[0];
#pragma unroll
    for (int m = 1; m < 64; m <<= 1) {
      unsigned long long ov = __shfl_xor(bk, m, 64);
      bk = ov > bk ? ov : bk;
    }
    if (lane == 0) red[i&1][wv] = bk;
    __syncthreads();
    unsigned long long best = red[i&1][0];
#pragma unroll
    for (int w = 1; w < 4; ++w) { unsigned long long v = red[i&1][w]; if (v > best) best = v; }
    f = (NN-1) - (int)(best & 0xffffffffull);
  }
}

// ---------------- ball query: wave per group, ballot compaction, _rn fp32 ----------------
// Decision-equivalent to the literal sequential scan (verified interchangeable
// rounds 1-8); pad = N-1 (literal semantics, verified).
__global__ __launch_bounds__(256) void ball_kernel(const float* __restrict__ xyz,
                                                   const float4* __restrict__ newxyz,
                                                   int* __restrict__ ball) {
  int t = threadIdx.x;
  int lane = t & 63;
  int bs = blockIdx.x*4 + (t >> 6);
  int b = bs >> 10;
  const float* xb = xyz + (size_t)b*3*NN;
  float4 c = newxyz[bs];
  float sumS = sq3(c.x, c.y, c.z);
  int count = 0;
  for (int ch = 0; ch < NN/64; ++ch) {
    int n = ch*64 + lane;
    float nx = xb[n], ny = xb[NN+n], nz = xb[2*NN+n];
    float sumN = sq3(nx, ny, nz);
    float dt   = __fadd_rn(__fadd_rn(__fmul_rn(c.x,nx), __fmul_rn(c.y,ny)), __fmul_rn(c.z,nz));
    float sqr  = __fsub_rn(__fadd_rn(sumS, sumN), __fmul_rn(2.0f, dt));
    bool isin = !(sqr > 0.04f);
    unsigned long long mask = __ballot(isin);
    int pos = count + (int)__popcll(mask & ((1ull << lane) - 1ull));
    if (isin && pos < KK) ball[(size_t)bs*KK + pos] = n;
    count += (int)__popcll(mask);
    if (count >= KK) break;
  }
  if (count < KK && lane >= count && lane < KK) ball[(size_t)bs*KK + lane] = NN-1;
}

// ---------------- fused LDS-tiled recompute passes (verified) ----------------
template<int PASS>
__global__ __launch_bounds__(256) void fused_kernel(
    const float* __restrict__ pt, const float4* __restrict__ xyzt,
    const float4* __restrict__ newxyz, const int* __restrict__ ball,
    const float* __restrict__ W0g, const float* __restrict__ b0g,
    const float* __restrict__ W1g, const float* __restrict__ b1g,
    const float* __restrict__ W2g, const float* __restrict__ b2g,
    const float* __restrict__ stats,
    const float* __restrict__ g0, const float* __restrict__ be0,
    const float* __restrict__ g1, const float* __restrict__ be1,
    float* __restrict__ statsOut,
    float* __restrict__ ymax, float* __restrict__ ymin) {
  __shared__ float4 Xs4[128*17];     // 128 rows x 68 floats
  __shared__ float4 Wb4[68*16];      // up to 68 rows x 64 cols
  __shared__ float sc0[64], sh0[64], sc1[64], sh1[64];
  float* Wb = (float*)Wb4;

  int t = threadIdx.x;
  int tc = t & 15;
  int wv = t >> 6;
  int trs = (t >> 4) & 3;

  if constexpr (PASS >= 1) {
    if (t < 64) {
      float mean = stats[t] * (1.0f/MROWS);
      float var  = stats[64+t] * (1.0f/MROWS) - mean*mean;
      float s    = g0[t] / sqrtf(var + EPSV);
      sc0[t] = s; sh0[t] = be0[t] - mean*s;
    }
  }
  if constexpr (PASS == 2) {
    if (t < 64) {
      float mean = stats[128+t] * (1.0f/MROWS);
      float var  = stats[192+t] * (1.0f/MROWS) - mean*mean;
      float s    = g1[t] / sqrtf(var + EPSV);
      sc1[t] = s; sh1[t] = be1[t] - mean*s;
    }
  }

  float bj0[4], bj1[4], bj2[2][4];
#pragma unroll
  for (int j = 0; j < 4; ++j) {
    bj0[j] = b0g[tc*4 + j];
    if constexpr (PASS >= 1) bj1[j] = b1g[tc*4 + j];
    if constexpr (PASS == 2) { bj2[0][j] = b2g[tc*4 + j]; bj2[1][j] = b2g[64 + tc*4 + j]; }
  }

  float accS[4] = {0,0,0,0}, accQ[4] = {0,0,0,0};
  float accS2[2][4] = {{0,0,0,0},{0,0,0,0}};
  float accQ2[2][4] = {{0,0,0,0},{0,0,0,0}};

  auto loadW0 = [&]() {
    for (int idx = t; idx < 68*64; idx += 256) {
      int cc = idx >> 6, o = idx & 63;
      float v = 0.f;
      if (cc < 67) v = W0g[o*67 + (cc < 64 ? cc+3 : cc-64)];
      Wb[idx] = v;
    }
  };
  auto loadW64 = [&](const float* Wg) {
    for (int idx = t; idx < 64*64; idx += 256) {
      int cc = idx >> 6, o = idx & 63;
      Wb[idx] = Wg[o*64 + cc];
    }
  };
  auto conv = [&](int C4N, float (&acc)[8][4], const float (&bj)[4]) {
#pragma unroll
    for (int i = 0; i < 8; ++i)
#pragma unroll
      for (int j = 0; j < 4; ++j) acc[i][j] = bj[j];
    for (int c4 = 0; c4 < C4N; ++c4) {
      float4 a[8];
#pragma unroll
      for (int i = 0; i < 8; ++i) a[i] = Xs4[(32*wv + trs + 4*i)*17 + c4];
      float4 w0 = Wb4[(4*c4+0)*16 + tc];
      float4 w1 = Wb4[(4*c4+1)*16 + tc];
      float4 w2 = Wb4[(4*c4+2)*16 + tc];
      float4 w3 = Wb4[(4*c4+3)*16 + tc];
#pragma unroll
      for (int i = 0; i < 8; ++i) {
        acc[i][0] = fmaf(a[i].x, w0.x, acc[i][0]); acc[i][1] = fmaf(a[i].x, w0.y, acc[i][1]);
        acc[i][2] = fmaf(a[i].x, w0.z, acc[i][2]); acc[i][3] = fmaf(a[i].x, w0.w, acc[i][3]);
        acc[i][0] = fmaf(a[i].y, w1.x, acc[i][0]); acc[i][1] = fmaf(a[i].y, w1.y, acc[i][1]);
        acc[i][2] = fmaf(a[i].y, w1.z, acc[i][2]); acc[i][3] = fmaf(a[i].y, w1.w, acc[i][3]);
        acc[i][0] = fmaf(a[i].z, w2.x, acc[i][0]); acc[i][1] = fmaf(a[i].z, w2.y, acc[i][1]);
        acc[i][2] = fmaf(a[i].z, w2.z, acc[i][2]); acc[i][3] = fmaf(a[i].z, w2.w, acc[i][3]);
        acc[i][0] = fmaf(a[i].w, w3.x, acc[i][0]); acc[i][1] = fmaf(a[i].w, w3.y, acc[i][1]);
        acc[i][2] = fmaf(a[i].w, w3.z, acc[i][2]); acc[i][3] = fmaf(a[i].w, w3.w, acc[i][3]);
      }
    }
  };
  auto bnstore = [&](float (&acc)[8][4], const float* sc, const float* sh) {
    float s0 = sc[tc*4], s1 = sc[tc*4+1], s2 = sc[tc*4+2], s3 = sc[tc*4+3];
    float h0 = sh[tc*4], h1 = sh[tc*4+1], h2 = sh[tc*4+2], h3 = sh[tc*4+3];
#pragma unroll
    for (int i = 0; i < 8; ++i)
      Xs4[(32*wv + trs + 4*i)*17 + tc] = make_float4(
          fmaxf(0.f, fmaf(acc[i][0], s0, h0)), fmaxf(0.f, fmaf(acc[i][1], s1, h1)),
          fmaxf(0.f, fmaf(acc[i][2], s2, h2)), fmaxf(0.f, fmaf(acc[i][3], s3, h3)));
  };
  auto accum = [&](float (&acc)[8][4], float (&aS)[4], float (&aQ)[4]) {
#pragma unroll
    for (int i = 0; i < 8; ++i)
#pragma unroll
      for (int j = 0; j < 4; ++j) { float v = acc[i][j]; aS[j] += v; aQ[j] = fmaf(v, v, aQ[j]); }
  };
  auto maxmin = [&](float (&acc)[8][4], int h, int tile) {
    float vmx[4], vmn[4];
#pragma unroll
    for (int j = 0; j < 4; ++j) {
      float mx = acc[0][j], mn = acc[0][j];
#pragma unroll
      for (int i = 1; i < 8; ++i) { mx = fmaxf(mx, acc[i][j]); mn = fminf(mn, acc[i][j]); }
      vmx[j] = mx; vmn[j] = mn;
    }
#pragma unroll
    for (int m = 16; m <= 32; m <<= 1)
#pragma unroll
      for (int j = 0; j < 4; ++j) {
        vmx[j] = fmaxf(vmx[j], __shfl_xor(vmx[j], m, 64));
        vmn[j] = fminf(vmn[j], __shfl_xor(vmn[j], m, 64));
      }
    if ((t & 63) < 16) {
      size_t gg = (size_t)tile*4 + wv;
      ((float4*)(ymax + gg*128 + h*64 + tc*4))[0] = make_float4(vmx[0], vmx[1], vmx[2], vmx[3]);
      ((float4*)(ymin + gg*128 + h*64 + tc*4))[0] = make_float4(vmn[0], vmn[1], vmn[2], vmn[3]);
    }
  };

  for (int tile = blockIdx.x; tile < MROWS/128; tile += gridDim.x) {
    {
      int rr = t >> 1, p = t & 1;
      int r = tile*128 + rr;
      int n = ball[r];
      int bb2 = r >> 15;
      const float4* src = (const float4*)(pt + ((size_t)(bb2*NN + n))*64) + 8*p;
#pragma unroll
      for (int jj = 0; jj < 8; ++jj) Xs4[rr*17 + 8*p + jj] = src[jj];
      if (p == 0) {
        float4 pz = xyzt[bb2*NN + n];
        float4 q  = newxyz[r >> 5];
        float* X = (float*)Xs4;
        X[rr*68 + 64] = pz.x - q.x;
        X[rr*68 + 65] = pz.y - q.y;
        X[rr*68 + 66] = pz.z - q.z;
        X[rr*68 + 67] = 0.f;
      }
    }
    loadW0();
    __syncthreads();

    float acc[8][4];
    conv(17, acc, bj0);
    if constexpr (PASS == 0) {
      accum(acc, accS, accQ);
      __syncthreads();
      continue;
    }

    __syncthreads();
    bnstore(acc, sc0, sh0);
    loadW64(W1g);
    __syncthreads();

    float acc1[8][4];
    conv(16, acc1, bj1);
    if constexpr (PASS == 1) {
      accum(acc1, accS, accQ);
      __syncthreads();
      continue;
    }

    if constexpr (PASS == 2) {
      __syncthreads();
      bnstore(acc1, sc1, sh1);
      loadW64(W2g);
      __syncthreads();

      float acc2[8][4];
      conv(16, acc2, bj2[0]);
      accum(acc2, accS2[0], accQ2[0]);
      maxmin(acc2, 0, tile);
      __syncthreads();
      loadW64(W2g + 64*64);
      __syncthreads();

      conv(16, acc2, bj2[1]);
      accum(acc2, accS2[1], accQ2[1]);
      maxmin(acc2, 1, tile);
      __syncthreads();
    }
  }

  float* scratch = (float*)Xs4;
  constexpr int NSTAT = (PASS == 2) ? 256 : 128;
  if (t < NSTAT) scratch[t] = 0.f;
  __syncthreads();
  if constexpr (PASS <= 1) {
#pragma unroll
    for (int j = 0; j < 4; ++j) {
      atomicAdd(&scratch[tc*4 + j], accS[j]);
      atomicAdd(&scratch[64 + tc*4 + j], accQ[j]);
    }
  } else {
#pragma unroll
    for (int h = 0; h < 2; ++h)
#pragma unroll
      for (int j = 0; j < 4; ++j) {
        atomicAdd(&scratch[h*64 + tc*4 + j], accS2[h][j]);
        atomicAdd(&scratch[128 + h*64 + tc*4 + j], accQ2[h][j]);
      }
  }
  __syncthreads();
  if (t < NSTAT) atomicAdd(&statsOut[t], scratch[t]);
}

// ---------------- epilogue: BN2+relu on max/min-pooled conv2, transposed write ----------------
__global__ __launch_bounds__(256) void final_kernel(const float4* __restrict__ ymax4,
                                                    const float4* __restrict__ ymin4,
                                                    const float* __restrict__ stats2,
                                                    const float* __restrict__ g2,
                                                    const float* __restrict__ be2,
                                                    float* __restrict__ out) {
  __shared__ float sc3[128], sh3[128];
  __shared__ float tile[64*129];
  int t = threadIdx.x;
  if (t < 128) {
    float mean = stats2[t] * (1.0f/MROWS);
    float var  = stats2[128+t] * (1.0f/MROWS) - mean*mean;
    float sc   = g2[t] / sqrtf(var + EPSV);
    sc3[t] = sc; sh3[t] = be2[t] - mean*sc;
  }
  __syncthreads();
  int b = blockIdx.x, s0 = blockIdx.y*64;
#pragma unroll
  for (int pass = 0; pass < 8; ++pass) {
    int srow = pass*8 + (t >> 5);
    int o4 = (t & 31)*4;
    size_t base = (size_t)(b*SS + s0 + srow)*32 + (t & 31);
    float4 vx = ymax4[base], vn = ymin4[base];
#pragma unroll
    for (int e = 0; e < 4; ++e) {
      int o = o4 + e;
      float sc = sc3[o];
      float v = sc > 0.f ? ((const float*)&vx)[e] : ((const float*)&vn)[e];
      tile[srow*129 + o] = fmaxf(0.f, fmaf(v, sc, sh3[o]));
    }
  }
  __syncthreads();
  int s = t & 63;
  size_t obase = (size_t)OUT_OFF1 + (size_t)b*128*SS + s0 + s;
#pragma unroll
  for (int oi = 0; oi < 32; ++oi) {
    int o = (t >> 6) + 4*oi;
    out[obase + (size_t)o*SS] = tile[s*129 + o];
  }
}

extern "C" void kernel_launch(void* const* d_in, const int* in_sizes, int n_in,
                              void* d_out, int out_size, void* d_ws, size_t ws_size,
                              hipStream_t stream) {
  const float* xyz = (const float*)d_in[0];
  const float* pts = (const float*)d_in[1];
  const float* W0  = (const float*)d_in[2];
  const float* b0  = (const float*)d_in[3];
  const float* g0  = (const float*)d_in[4];
  const float* be0 = (const float*)d_in[5];
  const float* W1  = (const float*)d_in[6];
  const float* b1  = (const float*)d_in[7];
  const float* g1  = (const float*)d_in[8];
  const float* be1 = (const float*)d_in[9];
  const float* W2  = (const float*)d_in[10];
  const float* b2  = (const float*)d_in[11];
  const float* g2  = (const float*)d_in[12];
  const float* be2 = (const float*)d_in[13];
  float* out = (float*)d_out;
  char* ws = (char*)d_ws;

  float4* xyzt   = (float4*)(ws + OFF_XYZT);
  float4* newxyz = (float4*)(ws + OFF_NEWXYZ);
  int*    ball   = (int*)(ws + OFF_BALL);
  float*  stats  = (float*)(ws + OFF_STATS);
  float*  pt     = (float*)(ws + OFF_PT);
  float*  ymax   = (float*)(ws + OFF_YMAX);
  float*  ymin   = (float*)(ws + OFF_YMIN);

  hipMemsetAsync(stats, 0, 512*sizeof(float), stream);
  fps_trans_kernel<<<16 + BB*(NN/64), 256, 0, stream>>>(xyz, pts, xyzt, pt, newxyz, out);
  ball_kernel<<<BB*SS/4, 256, 0, stream>>>(xyz, newxyz, ball);
  fused_kernel<0><<<1024, 256, 0, stream>>>(pt, xyzt, newxyz, ball, W0, b0, W1, b1, W2, b2,
      stats, g0, be0, g1, be1, stats, ymax, ymin);
  fused_kernel<1><<<1024, 256, 0, stream>>>(pt, xyzt, newxyz, ball, W0, b0, W1, b1, W2, b2,
      stats, g0, be0, g1, be1, stats + 128, ymax, ymin);
  fused_kernel<2><<<1024, 256, 0, stream>>>(pt, xyzt, newxyz, ball, W0, b0, W1, b1, W2, b2,
      stats, g0, be0, g1, be1, stats + 256, ymax, ymin);
  final_kernel<<<dim3(BB, SS/64), 256, 0, stream>>>((const float4*)ymax, (const float4*)ymin,
      stats + 256, g2, be2, out);
}